// Round 4
// baseline (273.025 us; speedup 1.0000x reference)
//
#include <hip/hip_runtime.h>
#include <math.h>
#include <stdint.h>

typedef __bf16 bf16;
typedef bf16 bf16x2 __attribute__((ext_vector_type(2)));
typedef bf16 bf16x8 __attribute__((ext_vector_type(8)));
typedef short s16x4 __attribute__((ext_vector_type(4)));
typedef float floatx4 __attribute__((ext_vector_type(4)));

static constexpr int Sq = 2048, Dm = 1024, Hh = 16, HDim = 64;

#define GAS __attribute__((address_space(1)))
#define LAS __attribute__((address_space(3)))

// async global->LDS DMA, 16 B per lane; lds base wave-uniform, lane i -> base + i*16
__device__ __forceinline__ void dma16(const void* g, void* l) {
    __builtin_amdgcn_global_load_lds((const GAS void*)g, (LAS void*)l, 16, 0, 0);
}

__device__ __forceinline__ uint32_t pk_bf16(float a, float b) {
    bf16x2 t;
    t[0] = (bf16)a;
    t[1] = (bf16)b;
    return __builtin_bit_cast(uint32_t, t);   // v_cvt_pk_bf16_f32 on gfx950
}

// ---------------------------------------------------------------------------
// Kernel 0: merged prep.  z<4: W fp32 [k][n] -> Wt bf16 [n][k] (w = z).
// z==4: x fp32 -> bf16 (256 blocks sweep 16x).
// ---------------------------------------------------------------------------
__global__ __launch_bounds__(256)
void prep_all(const float* __restrict__ Wq, const float* __restrict__ Wk,
              const float* __restrict__ Wv, const float* __restrict__ Wo,
              bf16* __restrict__ Wt,
              const float* __restrict__ x, bf16* __restrict__ xb)
{
    const int t = threadIdx.x;
    if (blockIdx.z == 4) {
        const int b = blockIdx.y * 16 + blockIdx.x;     // 0..255
        const size_t base = ((size_t)b * 256 + t) * 8;
#pragma unroll
        for (int it = 0; it < 16; it++) {
            const size_t i = base + (size_t)it * 524288;   // 256*256*8
            float4 f0 = *(const float4*)(x + i);
            float4 f1 = *(const float4*)(x + i + 4);
            bf16x8 v;
            v[0]=(bf16)f0.x; v[1]=(bf16)f0.y; v[2]=(bf16)f0.z; v[3]=(bf16)f0.w;
            v[4]=(bf16)f1.x; v[5]=(bf16)f1.y; v[6]=(bf16)f1.z; v[7]=(bf16)f1.w;
            *(bf16x8*)(xb + i) = v;
        }
        return;
    }
    const int w = blockIdx.z;
    const float* W = (w == 0) ? Wq : (w == 1) ? Wk : (w == 2) ? Wv : Wo;
    bf16* dst = Wt + (size_t)w * 1024 * 1024;
    const int k0 = blockIdx.x * 64, n0 = blockIdx.y * 64;
    __shared__ uint32_t Tl[64][33];
    {
        const int c8 = (t & 7) * 8;
        const int kp = t >> 3;
        const float* r0 = W + (size_t)(k0 + 2 * kp) * 1024 + n0 + c8;
        const float* r1 = r0 + 1024;
        float4 a0 = *(const float4*)r0, a1 = *(const float4*)(r0 + 4);
        float4 b0 = *(const float4*)r1, b1 = *(const float4*)(r1 + 4);
        float ra[8] = {a0.x, a0.y, a0.z, a0.w, a1.x, a1.y, a1.z, a1.w};
        float rb[8] = {b0.x, b0.y, b0.z, b0.w, b1.x, b1.y, b1.z, b1.w};
#pragma unroll
        for (int j = 0; j < 8; j++)
            Tl[c8 + j][kp] = pk_bf16(ra[j], rb[j]);
    }
    __syncthreads();
    {
        const int c = t >> 2, dq = (t & 3) * 8;
        uint32_t d[8];
#pragma unroll
        for (int i = 0; i < 8; i++) d[i] = Tl[c][dq + i];
        uint32_t* o = (uint32_t*)(dst + (size_t)(n0 + c) * 1024 + k0 + dq * 2);
        *(uint4*)o       = make_uint4(d[0], d[1], d[2], d[3]);
        *(uint4*)(o + 4) = make_uint4(d[4], d[5], d[6], d[7]);
    }
}

// ---------------------------------------------------------------------------
// Kernel 1: QKV projection.  AMODE=1: bf16 xb via DMA (primary);
// AMODE=0: fp32 x (fallback).  128x128 tile, BK=64.
// grid (64 Mtiles, 8 Ntiles, 3): XCD = Mtile%8 -> A-tile reuse in XCD L2.
// K output pre-scaled by 0.125*log2(e) (softmax runs in exp2 domain).
// ---------------------------------------------------------------------------
template <int AMODE>
__global__ __launch_bounds__(256, 2)
void qkv_gemm(const float* __restrict__ x, const bf16* __restrict__ xb,
              const bf16* __restrict__ Wt,
              bf16* __restrict__ Qb, bf16* __restrict__ Kb, bf16* __restrict__ VT)
{
    const int zz = blockIdx.z;
    const bf16* Wsel = Wt + (size_t)zz * 1024 * 1024;

    __shared__ __align__(16) unsigned char smem[34816];
    bf16 (*As1)[64] = (bf16(*)[64])smem;
    bf16 (*As0)[72] = (bf16(*)[72])smem;
    bf16 (*Bs)[64]  = (bf16(*)[64])(smem + (AMODE ? 16384 : 18432));

    const int tid  = threadIdx.x;
    const int wave = tid >> 6, lane = tid & 63, quad = lane >> 4, l16 = lane & 15;
    const int bm = blockIdx.x * 128, bn = blockIdx.y * 128;   // XCD = blockIdx.x % 8
    const int wm = (wave >> 1) * 64, wn = (wave & 1) * 64;

    floatx4 acc[4][4];
#pragma unroll
    for (int i = 0; i < 4; i++)
#pragma unroll
        for (int j = 0; j < 4; j++) acc[i][j] = (floatx4){0.f, 0.f, 0.f, 0.f};

    for (int k0 = 0; k0 < 1024; k0 += 64) {
        __syncthreads();
#pragma unroll
        for (int i = 0; i < 4; i++) {
            const int row = wave * 32 + i * 8 + (lane >> 3);
            const int lb  = (lane & 7) ^ (row & 7);
            const bf16* g = Wsel + (size_t)(bn + row) * 1024 + k0 + lb * 8;
            dma16((const void*)g, (void*)&Bs[wave * 32 + i * 8][0]);
        }
        if (AMODE) {
#pragma unroll
            for (int i = 0; i < 4; i++) {
                const int row = wave * 32 + i * 8 + (lane >> 3);
                const int lb  = (lane & 7) ^ (row & 7);
                const bf16* g = xb + (size_t)(bm + row) * 1024 + k0 + lb * 8;
                dma16((const void*)g, (void*)&As1[wave * 32 + i * 8][0]);
            }
        } else {
#pragma unroll
            for (int it = 0; it < 2; it++) {
                const int r  = (tid >> 2) + it * 64;
                const int cq = (tid & 3) * 16;
                const float* src = x + (size_t)(bm + r) * 1024 + k0 + cq;
                float4 f0 = *(const float4*)src,       f1 = *(const float4*)(src + 4);
                float4 f2 = *(const float4*)(src + 8), f3 = *(const float4*)(src + 12);
                bf16x8 v0, v1;
                v0[0]=(bf16)f0.x; v0[1]=(bf16)f0.y; v0[2]=(bf16)f0.z; v0[3]=(bf16)f0.w;
                v0[4]=(bf16)f1.x; v0[5]=(bf16)f1.y; v0[6]=(bf16)f1.z; v0[7]=(bf16)f1.w;
                v1[0]=(bf16)f2.x; v1[1]=(bf16)f2.y; v1[2]=(bf16)f2.z; v1[3]=(bf16)f2.w;
                v1[4]=(bf16)f3.x; v1[5]=(bf16)f3.y; v1[6]=(bf16)f3.z; v1[7]=(bf16)f3.w;
                *(bf16x8*)&As0[r][cq]     = v0;
                *(bf16x8*)&As0[r][cq + 8] = v1;
            }
        }
        __syncthreads();

#pragma unroll
        for (int kk = 0; kk < 2; kk++) {
            bf16x8 a[4], b[4];
#pragma unroll
            for (int tm = 0; tm < 4; tm++) {
                const int m = wm + tm * 16 + l16;
                if (AMODE) {
                    const int phys = (kk * 4 + quad) ^ (m & 7);
                    a[tm] = *(const bf16x8*)&As1[m][phys * 8];
                } else {
                    a[tm] = *(const bf16x8*)&As0[m][kk * 32 + quad * 8];
                }
            }
#pragma unroll
            for (int tn = 0; tn < 4; tn++) {
                const int n = wn + tn * 16 + l16;
                const int phys = (kk * 4 + quad) ^ (n & 7);
                b[tn] = *(const bf16x8*)&Bs[n][phys * 8];
            }
#pragma unroll
            for (int tm = 0; tm < 4; tm++)
#pragma unroll
                for (int tn = 0; tn < 4; tn++)
                    acc[tm][tn] = __builtin_amdgcn_mfma_f32_16x16x32_bf16(a[tm], b[tn], acc[tm][tn], 0, 0, 0);
        }
    }

    if (zz < 2) {
        bf16* dst = (zz == 0) ? Qb : Kb;
        // K pre-scaled by 1/sqrt(64) * log2(e): softmax in exp2 domain
        const float sc = (zz == 1) ? 0.18033688f : 1.0f;
#pragma unroll
        for (int tm = 0; tm < 4; tm++)
#pragma unroll
            for (int tn = 0; tn < 4; tn++)
#pragma unroll
                for (int r = 0; r < 4; r++) {
                    const int m = bm + wm + tm * 16 + quad * 4 + r;
                    const int n = bn + wn + tn * 16 + l16;
                    const int bb = m >> 11, s = m & 2047;
                    const int h = n >> 6, d = n & 63;
                    dst[(((size_t)(bb * Hh + h)) * Sq + s) * HDim + d] = (bf16)(acc[tm][tn][r] * sc);
                }
    } else {
        __syncthreads();
        bf16 (*CT)[136] = (bf16(*)[136])smem;
#pragma unroll
        for (int tm = 0; tm < 4; tm++)
#pragma unroll
            for (int tn = 0; tn < 4; tn++)
#pragma unroll
                for (int r = 0; r < 4; r++) {
                    const int ml = wm + tm * 16 + quad * 4 + r;
                    const int nl = wn + tn * 16 + l16;
                    CT[nl][ml] = (bf16)acc[tm][tn][r];
                }
        __syncthreads();
        const int nl = tid >> 1, part = tid & 1;
        const int n = bn + nl, h = n >> 6, d = n & 63;
        const int bbv = bm >> 11, s0v = bm & 2047;
        bf16* o = VT + (((size_t)(bbv * Hh + h)) * HDim + d) * Sq + s0v + part * 64;
#pragma unroll
        for (int i = 0; i < 8; i++)
            *(bf16x8*)(o + i * 8) = *(const bf16x8*)&CT[nl][part * 64 + i * 8];
    }
}

// ---------------------------------------------------------------------------
// Kernel 2: flash-style causal attention, S-transposed, fixed-reference
// softmax.  v5: KEY-SLICED wave decomposition with K=16 PV MFMA.
// 4 waves; wave w owns keys [16w,16w+16) of each 64-key tile, computes
// partial O for ALL 64 qrows.  QK^T C-layout (key=quad*4+r, q=l16) is
// EXACTLY the B-fragment layout of v_mfma_f32_16x16x16_bf16 (K=16) ->
// P flows softmax->PV fully in registers, no LDS round-trip, and unlike
// v4 the 16-key contraction wastes NO matrix-pipe cycles (v4 issued it
// as K=32 with a zeroed upper half -> 1.5x MFMA busy-cycles, regressed).
// Per wave-tile: 8 MFMA_x32 (QK) + 16 MFMA_x16 (PV) ~ 78 cyc issue, and
// ~1 KB LDS reads (own K-slice 2xb128 + 16-key V columns 4xb64).
// Partial O (acc[j] = d-quarter (wave+j)&3) cross-wave reduced through an
// LDS overlay at block end.  Grid (64 bh, 32 qt), LPT order, double-
// buffered K/V DMA, counted vmcnt(4), raw barriers, setprio on MFMA.
// ---------------------------------------------------------------------------
__global__ __launch_bounds__(256, 4)
void attn(const bf16* __restrict__ Qb, const bf16* __restrict__ Kb,
          const bf16* __restrict__ VTg, bf16* __restrict__ Cx)
{
    const int bh = blockIdx.x;                 // XCD = bh % 8 (qt-steps keep XCD)
    const int bl = bh >> 4, h = bh & 15;
    const int qt = 31 - (int)blockIdx.y;       // LPT: longest blocks first
    const int q0 = qt * 64;
    const int nk = qt + 1;

    __shared__ __align__(16) char smem[33792];
    bf16 (*Kl)[64][64] = (bf16(*)[64][64])smem;              // [2][key][d]
    bf16 (*Vt)[64][64] = (bf16(*)[64][64])(smem + 16384);    // [2][d][key]
    float (*Rq)[64][20] = (float(*)[64][20])smem;            // overlay: [src][q][d16+pad]
    float (*Lred)[4][16] = (float(*)[4][16])(smem + 32768);  // [wave][nt][l16]

    const int tid  = threadIdx.x;
    const int wave = tid >> 6, lane = tid & 63, quad = lane >> 4, l16 = lane & 15;

    // staging: wave w stages its own K key-rows and the d-rows 16w..16w+15 of V
    const int srow = wave * 16 + (lane >> 3);
    const int lb   = (lane & 7) ^ (lane >> 3);     // 16B-slot source swizzle

    // Q^T B-fragments for ALL 64 q-cols (loop-invariant, 32 VGPRs)
    bf16x8 bq[4][2];
#pragma unroll
    for (int nt = 0; nt < 4; nt++) {
        const bf16* Qrow = Qb + ((size_t)bh * Sq + q0 + nt * 16 + l16) * HDim;
        bq[nt][0] = *(const bf16x8*)(Qrow + quad * 8);
        bq[nt][1] = *(const bf16x8*)(Qrow + 32 + quad * 8);
    }

    floatx4 acc[4][4];     // [j][nt]; acc[j] = d-quarter (wave+j)&3
#pragma unroll
    for (int i = 0; i < 4; i++)
#pragma unroll
        for (int j = 0; j < 4; j++) acc[i][j] = (floatx4){0.f, 0.f, 0.f, 0.f};
    float l_part[4] = {0.f, 0.f, 0.f, 0.f};

    const bf16* kp = Kb  + ((size_t)bh * Sq + srow) * HDim + lb * 8;
    const bf16* vp = VTg + ((size_t)bh * HDim + srow) * Sq + lb * 8;

    // issue the 4 DMA ops for one k-tile into buffer nb, advance pointers
    auto stage = [&](int nb) {
#pragma unroll
        for (int i = 0; i < 2; i++) {
            dma16((const void*)(kp + (size_t)(i * 8) * HDim), (void*)&Kl[nb][wave * 16 + i * 8][0]);
            dma16((const void*)(vp + (size_t)(i * 8) * Sq),  (void*)&Vt[nb][wave * 16 + i * 8][0]);
        }
        kp += 64 * HDim;
        vp += 64;
    };

    // compute one k-tile from buffer nb; MASKED known at compile time
    auto tile = [&](int nb, bool masked) {
        const bf16 (*Ksm)[64] = Kl[nb];
        const bf16 (*Vsm)[64] = Vt[nb];

        // K A-fragment: this wave's 16 key-rows only
        const int kr = wave * 16 + l16;
        const bf16x8 ak0 = *(const bf16x8*)&Ksm[kr][(quad ^ (kr & 7)) * 8];
        const bf16x8 ak1 = *(const bf16x8*)&Ksm[kr][((4 + quad) ^ (kr & 7)) * 8];

        // QK^T + softmax, streamed per nt; P packs directly into K=16
        // PV B-fragments (2 VGPRs: keys quad*4+0..3, col l16)
        s16x4 pb[4];
#pragma unroll
        for (int nt = 0; nt < 4; nt++) {
            floatx4 z = (floatx4){0.f, 0.f, 0.f, 0.f};
            __builtin_amdgcn_s_setprio(1);
            z = __builtin_amdgcn_mfma_f32_16x16x32_bf16(ak0, bq[nt][0], z, 0, 0, 0);
            z = __builtin_amdgcn_mfma_f32_16x16x32_bf16(ak1, bq[nt][1], z, 0, 0, 0);
            __builtin_amdgcn_s_setprio(0);
            if (masked) {
#pragma unroll
                for (int r = 0; r < 4; r++) {
                    const int keyl = wave * 16 + quad * 4 + r;
                    if (keyl > nt * 16 + l16) z[r] = -1e30f;
                }
            }
            float rs = 0.f;
#pragma unroll
            for (int r = 0; r < 4; r++) {
                const float e = __builtin_amdgcn_exp2f(z[r]);
                z[r] = e;
                rs += e;
            }
            l_part[nt] += rs;
            const uint2 pk = make_uint2(pk_bf16(z[0], z[1]), pk_bf16(z[2], z[3]));
            pb[nt] = __builtin_bit_cast(s16x4, pk);
        }

        // O^T partial += V^T(slice) . P^T via K=16 MFMA: A-frag = 4 bf16
        // of V^T[d=row][key=16w+quad*4+0..3].  acc[j] = d-quarter (wave+j)&3.
#pragma unroll
        for (int j = 0; j < 4; j++) {
            const int row = ((wave + j) & 3) * 16 + l16;
            const int sl  = ((wave * 2 + (quad >> 1)) ^ (row & 7)) * 16 + (quad & 1) * 8;
            const uint2 v = *(const uint2*)((const char*)&Vsm[row][0] + sl);
            const s16x4 av = __builtin_bit_cast(s16x4, v);
            __builtin_amdgcn_s_setprio(1);
#pragma unroll
            for (int nt = 0; nt < 4; nt++)
                acc[j][nt] = __builtin_amdgcn_mfma_f32_16x16x16bf16_1k(av, pb[nt], acc[j][nt], 0, 0, 0);
            __builtin_amdgcn_s_setprio(0);
        }
    };

    // pipelined loop: stage(t+1) in flight while computing tile t.
    // vmcnt(4): newest 4 vmem ops are tile t+1's DMAs.  RAW barrier: each
    // wave waited for its own loads pre-barrier -> all LDS writes visible.
    stage(0);
    for (int kt = 0; kt < nk - 1; kt++) {
        const int cur = kt & 1;
        stage(cur ^ 1);
        asm volatile("s_waitcnt vmcnt(4)" ::: "memory");
        __builtin_amdgcn_s_barrier();
        tile(cur, false);
        __builtin_amdgcn_s_barrier();
    }
    asm volatile("s_waitcnt vmcnt(0)" ::: "memory");
    __builtin_amdgcn_s_barrier();
    tile((nk - 1) & 1, true);               // peeled diagonal tile

    // ---- epilogue: cross-wave reduce of l and partial O ----
    float lw[4];
#pragma unroll
    for (int nt = 0; nt < 4; nt++) {
        float rs = l_part[nt];
        rs += __shfl_xor(rs, 16, 64);
        rs += __shfl_xor(rs, 32, 64);
        lw[nt] = rs;
    }
    __syncthreads();       // all waves done reading Kl/Vt before overlay use
    if (quad == 0) {
#pragma unroll
        for (int nt = 0; nt < 4; nt++) Lred[wave][nt][l16] = lw[nt];
    }
    // round 1: wave w publishes acc[1] (= d-quarter (w+1)&3)
#pragma unroll
    for (int nt = 0; nt < 4; nt++)
        *(floatx4*)&Rq[wave][nt * 16 + l16][quad * 4] = acc[1][nt];
    __syncthreads();
    float lsum[4];
#pragma unroll
    for (int nt = 0; nt < 4; nt++)
        lsum[nt] = Lred[0][nt][l16] + Lred[1][nt][l16] + Lred[2][nt][l16] + Lred[3][nt][l16];
#pragma unroll
    for (int nt = 0; nt < 4; nt++)
        acc[0][nt] += *(const floatx4*)&Rq[(wave + 3) & 3][nt * 16 + l16][quad * 4];
    __syncthreads();
    // round 2
#pragma unroll
    for (int nt = 0; nt < 4; nt++)
        *(floatx4*)&Rq[wave][nt * 16 + l16][quad * 4] = acc[2][nt];
    __syncthreads();
#pragma unroll
    for (int nt = 0; nt < 4; nt++)
        acc[0][nt] += *(const floatx4*)&Rq[(wave + 2) & 3][nt * 16 + l16][quad * 4];
    __syncthreads();
    // round 3
#pragma unroll
    for (int nt = 0; nt < 4; nt++)
        *(floatx4*)&Rq[wave][nt * 16 + l16][quad * 4] = acc[3][nt];
    __syncthreads();
#pragma unroll
    for (int nt = 0; nt < 4; nt++)
        acc[0][nt] += *(const floatx4*)&Rq[(wave + 1) & 3][nt * 16 + l16][quad * 4];

    // write: wave w owns d-quarter w for all 64 qrows
#pragma unroll
    for (int nt = 0; nt < 4; nt++) {
        const float inv = __builtin_amdgcn_rcpf(lsum[nt]);
        uint2 pk;
        pk.x = pk_bf16(acc[0][nt][0] * inv, acc[0][nt][1] * inv);
        pk.y = pk_bf16(acc[0][nt][2] * inv, acc[0][nt][3] * inv);
        const int qrow = q0 + nt * 16 + l16;
        *(uint2*)(Cx + ((size_t)(bl * Sq + qrow)) * Dm + h * HDim + wave * 16 + quad * 4) = pk;
    }
}

// ---------------------------------------------------------------------------
// Kernel 3: output projection.  Cx bf16 @ WoT + bo -> fp32 out.
// grid (Mtiles, 8): XCD = Mtile%8 for A-tile L2 reuse.
// ---------------------------------------------------------------------------
__global__ __launch_bounds__(256, 2)
void out_gemm(const bf16* __restrict__ Cx, const bf16* __restrict__ WtO,
              const float* __restrict__ bo, float* __restrict__ out, int mbase)
{
    __shared__ __align__(16) bf16 As2[128][64];
    __shared__ __align__(16) bf16 Bs2[128][64];

    const int tid  = threadIdx.x;
    const int wave = tid >> 6, lane = tid & 63, quad = lane >> 4, l16 = lane & 15;
    const int bm = blockIdx.x * 128, bn = blockIdx.y * 128;
    const int wm = (wave >> 1) * 64, wn = (wave & 1) * 64;

    floatx4 acc[4][4];
#pragma unroll
    for (int i = 0; i < 4; i++)
#pragma unroll
        for (int j = 0; j < 4; j++) acc[i][j] = (floatx4){0.f, 0.f, 0.f, 0.f};

    for (int k0 = 0; k0 < 1024; k0 += 64) {
        __syncthreads();
#pragma unroll
        for (int i = 0; i < 4; i++) {
            const int row = wave * 32 + i * 8 + (lane >> 3);
            const int lb  = (lane & 7) ^ (row & 7);
            const bf16* ga = Cx  + (size_t)(bm + row) * 1024 + k0 + lb * 8;
            const bf16* gb = WtO + (size_t)(bn + row) * 1024 + k0 + lb * 8;
            dma16((const void*)ga, (void*)&As2[wave * 32 + i * 8][0]);
            dma16((const void*)gb, (void*)&Bs2[wave * 32 + i * 8][0]);
        }
        __syncthreads();

#pragma unroll
        for (int kk = 0; kk < 2; kk++) {
            bf16x8 a[4], b[4];
#pragma unroll
            for (int tm = 0; tm < 4; tm++) {
                const int m = wm + tm * 16 + l16;
                const int phys = (kk * 4 + quad) ^ (m & 7);
                a[tm] = *(const bf16x8*)&As2[m][phys * 8];
            }
#pragma unroll
            for (int tn = 0; tn < 4; tn++) {
                const int n = wn + tn * 16 + l16;
                const int phys = (kk * 4 + quad) ^ (n & 7);
                b[tn] = *(const bf16x8*)&Bs2[n][phys * 8];
            }
#pragma unroll
            for (int tm = 0; tm < 4; tm++)
#pragma unroll
                for (int tn = 0; tn < 4; tn++)
                    acc[tm][tn] = __builtin_amdgcn_mfma_f32_16x16x32_bf16(a[tm], b[tn], acc[tm][tn], 0, 0, 0);
        }
    }

#pragma unroll
    for (int tm = 0; tm < 4; tm++)
#pragma unroll
        for (int tn = 0; tn < 4; tn++)
#pragma unroll
            for (int r = 0; r < 4; r++) {
                const int m = bm + wm + tm * 16 + quad * 4 + r;
                const int n = bn + wn + tn * 16 + l16;
                out[(size_t)(mbase + m) * 1024 + n] = acc[tm][tn][r] + bo[n];
            }
}

// ---------------------------------------------------------------------------
extern "C" void kernel_launch(void* const* d_in, const int* in_sizes, int n_in,
                              void* d_out, int out_size, void* d_ws, size_t ws_size,
                              hipStream_t stream)
{
    const float* x  = (const float*)d_in[0];
    const float* Wq = (const float*)d_in[1];
    const float* Wk = (const float*)d_in[2];
    const float* Wv = (const float*)d_in[3];
    const float* Wo = (const float*)d_in[4];
    const float* bo = (const float*)d_in[5];
    float* out = (float*)d_out;

    const size_t M1 = 1024 * 1024;
    const size_t XE = (size_t)8192 * 1024;

    if (ws_size >= (size_t)72 * 1024 * 1024) {
        // primary: Wt 8MB | xb 16 (aliased by Cx) | Qb 16 | Kb 16 | VT 16
        bf16* Wt = (bf16*)d_ws;
        bf16* xb = Wt + 4 * M1;
        bf16* Qb = xb + XE;
        bf16* Kb = Qb + XE;
        bf16* VT = Kb + XE;
        bf16* Cx = xb;  // alias: xb dead after qkv_gemm

        prep_all<<<dim3(16, 16, 5), 256, 0, stream>>>(Wq, Wk, Wv, Wo, Wt, x, xb);
        qkv_gemm<1><<<dim3(64, 8, 3), 256, 0, stream>>>(x, xb, Wt, Qb, Kb, VT);
        attn<<<dim3(64, 32), 256, 0, stream>>>(Qb, Kb, VT, Cx);
        out_gemm<<<dim3(64, 8), 256, 0, stream>>>(Cx, Wt + 3 * M1, bo, out, 0);
    } else {
        // fallback (64 MB): Wt 8 | Qb 16 | Kb 16 | VT 16 | Cx 8
        bf16* Wt = (bf16*)d_ws;
        bf16* Qb = Wt + 4 * M1;
        bf16* Kb = Qb + XE;
        bf16* VT = Kb + XE;
        bf16* Cx = VT + XE;

        prep_all<<<dim3(16, 16, 4), 256, 0, stream>>>(Wq, Wk, Wv, Wo, Wt, nullptr, nullptr);
        qkv_gemm<0><<<dim3(64, 8, 3), 256, 0, stream>>>(x, nullptr, Wt, Qb, Kb, VT);
        const size_t chunk = (size_t)2 * Hh * Sq * HDim;
        for (int c = 0; c < 2; c++) {
            attn<<<dim3(32, 32), 256, 0, stream>>>(Qb + c * chunk, Kb + c * chunk,
                                                   VT + c * chunk, Cx);
            out_gemm<<<dim3(32, 8), 256, 0, stream>>>(Cx, Wt + 3 * M1, bo, out, c * 4096);
        }
    }
}

// Round 5
// 237.597 us; speedup vs baseline: 1.1491x; 1.1491x over previous
//
#include <hip/hip_runtime.h>
#include <math.h>
#include <stdint.h>

typedef __bf16 bf16;
typedef bf16 bf16x2 __attribute__((ext_vector_type(2)));
typedef bf16 bf16x8 __attribute__((ext_vector_type(8)));
typedef short s16x4 __attribute__((ext_vector_type(4)));
typedef float floatx4 __attribute__((ext_vector_type(4)));

static constexpr int Sq = 2048, Dm = 1024, Hh = 16, HDim = 64;

#define GAS __attribute__((address_space(1)))
#define LAS __attribute__((address_space(3)))

// async global->LDS DMA, 16 B per lane; lds base wave-uniform, lane i -> base + i*16
__device__ __forceinline__ void dma16(const void* g, void* l) {
    __builtin_amdgcn_global_load_lds((const GAS void*)g, (LAS void*)l, 16, 0, 0);
}

__device__ __forceinline__ uint32_t pk_bf16(float a, float b) {
    bf16x2 t;
    t[0] = (bf16)a;
    t[1] = (bf16)b;
    return __builtin_bit_cast(uint32_t, t);   // v_cvt_pk_bf16_f32 on gfx950
}

// ---------------------------------------------------------------------------
// Kernel 0: merged prep.  z<4: W fp32 [k][n] -> Wt bf16 [n][k] (w = z).
// z==4: x fp32 -> bf16 (256 blocks sweep 16x).
// ---------------------------------------------------------------------------
__global__ __launch_bounds__(256)
void prep_all(const float* __restrict__ Wq, const float* __restrict__ Wk,
              const float* __restrict__ Wv, const float* __restrict__ Wo,
              bf16* __restrict__ Wt,
              const float* __restrict__ x, bf16* __restrict__ xb)
{
    const int t = threadIdx.x;
    if (blockIdx.z == 4) {
        const int b = blockIdx.y * 16 + blockIdx.x;     // 0..255
        const size_t base = ((size_t)b * 256 + t) * 8;
#pragma unroll
        for (int it = 0; it < 16; it++) {
            const size_t i = base + (size_t)it * 524288;   // 256*256*8
            float4 f0 = *(const float4*)(x + i);
            float4 f1 = *(const float4*)(x + i + 4);
            bf16x8 v;
            v[0]=(bf16)f0.x; v[1]=(bf16)f0.y; v[2]=(bf16)f0.z; v[3]=(bf16)f0.w;
            v[4]=(bf16)f1.x; v[5]=(bf16)f1.y; v[6]=(bf16)f1.z; v[7]=(bf16)f1.w;
            *(bf16x8*)(xb + i) = v;
        }
        return;
    }
    const int w = blockIdx.z;
    const float* W = (w == 0) ? Wq : (w == 1) ? Wk : (w == 2) ? Wv : Wo;
    bf16* dst = Wt + (size_t)w * 1024 * 1024;
    const int k0 = blockIdx.x * 64, n0 = blockIdx.y * 64;
    __shared__ uint32_t Tl[64][33];
    {
        const int c8 = (t & 7) * 8;
        const int kp = t >> 3;
        const float* r0 = W + (size_t)(k0 + 2 * kp) * 1024 + n0 + c8;
        const float* r1 = r0 + 1024;
        float4 a0 = *(const float4*)r0, a1 = *(const float4*)(r0 + 4);
        float4 b0 = *(const float4*)r1, b1 = *(const float4*)(r1 + 4);
        float ra[8] = {a0.x, a0.y, a0.z, a0.w, a1.x, a1.y, a1.z, a1.w};
        float rb[8] = {b0.x, b0.y, b0.z, b0.w, b1.x, b1.y, b1.z, b1.w};
#pragma unroll
        for (int j = 0; j < 8; j++)
            Tl[c8 + j][kp] = pk_bf16(ra[j], rb[j]);
    }
    __syncthreads();
    {
        const int c = t >> 2, dq = (t & 3) * 8;
        uint32_t d[8];
#pragma unroll
        for (int i = 0; i < 8; i++) d[i] = Tl[c][dq + i];
        uint32_t* o = (uint32_t*)(dst + (size_t)(n0 + c) * 1024 + k0 + dq * 2);
        *(uint4*)o       = make_uint4(d[0], d[1], d[2], d[3]);
        *(uint4*)(o + 4) = make_uint4(d[4], d[5], d[6], d[7]);
    }
}

// ---------------------------------------------------------------------------
// Kernel 1: QKV projection.  AMODE=1: bf16 xb via DMA (primary);
// AMODE=0: fp32 x (fallback).  128x128 tile, BK=64.
// grid (64 Mtiles, 8 Ntiles, 3): XCD = Mtile%8 -> A-tile reuse in XCD L2.
// K output pre-scaled by 0.125*log2(e) (softmax runs in exp2 domain).
// ---------------------------------------------------------------------------
template <int AMODE>
__global__ __launch_bounds__(256, 2)
void qkv_gemm(const float* __restrict__ x, const bf16* __restrict__ xb,
              const bf16* __restrict__ Wt,
              bf16* __restrict__ Qb, bf16* __restrict__ Kb, bf16* __restrict__ VT)
{
    const int zz = blockIdx.z;
    const bf16* Wsel = Wt + (size_t)zz * 1024 * 1024;

    __shared__ __align__(16) unsigned char smem[34816];
    bf16 (*As1)[64] = (bf16(*)[64])smem;
    bf16 (*As0)[72] = (bf16(*)[72])smem;
    bf16 (*Bs)[64]  = (bf16(*)[64])(smem + (AMODE ? 16384 : 18432));

    const int tid  = threadIdx.x;
    const int wave = tid >> 6, lane = tid & 63, quad = lane >> 4, l16 = lane & 15;
    const int bm = blockIdx.x * 128, bn = blockIdx.y * 128;   // XCD = blockIdx.x % 8
    const int wm = (wave >> 1) * 64, wn = (wave & 1) * 64;

    floatx4 acc[4][4];
#pragma unroll
    for (int i = 0; i < 4; i++)
#pragma unroll
        for (int j = 0; j < 4; j++) acc[i][j] = (floatx4){0.f, 0.f, 0.f, 0.f};

    for (int k0 = 0; k0 < 1024; k0 += 64) {
        __syncthreads();
#pragma unroll
        for (int i = 0; i < 4; i++) {
            const int row = wave * 32 + i * 8 + (lane >> 3);
            const int lb  = (lane & 7) ^ (row & 7);
            const bf16* g = Wsel + (size_t)(bn + row) * 1024 + k0 + lb * 8;
            dma16((const void*)g, (void*)&Bs[wave * 32 + i * 8][0]);
        }
        if (AMODE) {
#pragma unroll
            for (int i = 0; i < 4; i++) {
                const int row = wave * 32 + i * 8 + (lane >> 3);
                const int lb  = (lane & 7) ^ (row & 7);
                const bf16* g = xb + (size_t)(bm + row) * 1024 + k0 + lb * 8;
                dma16((const void*)g, (void*)&As1[wave * 32 + i * 8][0]);
            }
        } else {
#pragma unroll
            for (int it = 0; it < 2; it++) {
                const int r  = (tid >> 2) + it * 64;
                const int cq = (tid & 3) * 16;
                const float* src = x + (size_t)(bm + r) * 1024 + k0 + cq;
                float4 f0 = *(const float4*)src,       f1 = *(const float4*)(src + 4);
                float4 f2 = *(const float4*)(src + 8), f3 = *(const float4*)(src + 12);
                bf16x8 v0, v1;
                v0[0]=(bf16)f0.x; v0[1]=(bf16)f0.y; v0[2]=(bf16)f0.z; v0[3]=(bf16)f0.w;
                v0[4]=(bf16)f1.x; v0[5]=(bf16)f1.y; v0[6]=(bf16)f1.z; v0[7]=(bf16)f1.w;
                v1[0]=(bf16)f2.x; v1[1]=(bf16)f2.y; v1[2]=(bf16)f2.z; v1[3]=(bf16)f2.w;
                v1[4]=(bf16)f3.x; v1[5]=(bf16)f3.y; v1[6]=(bf16)f3.z; v1[7]=(bf16)f3.w;
                *(bf16x8*)&As0[r][cq]     = v0;
                *(bf16x8*)&As0[r][cq + 8] = v1;
            }
        }
        __syncthreads();

#pragma unroll
        for (int kk = 0; kk < 2; kk++) {
            bf16x8 a[4], b[4];
#pragma unroll
            for (int tm = 0; tm < 4; tm++) {
                const int m = wm + tm * 16 + l16;
                if (AMODE) {
                    const int phys = (kk * 4 + quad) ^ (m & 7);
                    a[tm] = *(const bf16x8*)&As1[m][phys * 8];
                } else {
                    a[tm] = *(const bf16x8*)&As0[m][kk * 32 + quad * 8];
                }
            }
#pragma unroll
            for (int tn = 0; tn < 4; tn++) {
                const int n = wn + tn * 16 + l16;
                const int phys = (kk * 4 + quad) ^ (n & 7);
                b[tn] = *(const bf16x8*)&Bs[n][phys * 8];
            }
#pragma unroll
            for (int tm = 0; tm < 4; tm++)
#pragma unroll
                for (int tn = 0; tn < 4; tn++)
                    acc[tm][tn] = __builtin_amdgcn_mfma_f32_16x16x32_bf16(a[tm], b[tn], acc[tm][tn], 0, 0, 0);
        }
    }

    if (zz < 2) {
        bf16* dst = (zz == 0) ? Qb : Kb;
        // K pre-scaled by 1/sqrt(64) * log2(e): softmax in exp2 domain
        const float sc = (zz == 1) ? 0.18033688f : 1.0f;
#pragma unroll
        for (int tm = 0; tm < 4; tm++)
#pragma unroll
            for (int tn = 0; tn < 4; tn++)
#pragma unroll
                for (int r = 0; r < 4; r++) {
                    const int m = bm + wm + tm * 16 + quad * 4 + r;
                    const int n = bn + wn + tn * 16 + l16;
                    const int bb = m >> 11, s = m & 2047;
                    const int h = n >> 6, d = n & 63;
                    dst[(((size_t)(bb * Hh + h)) * Sq + s) * HDim + d] = (bf16)(acc[tm][tn][r] * sc);
                }
    } else {
        __syncthreads();
        bf16 (*CT)[136] = (bf16(*)[136])smem;
#pragma unroll
        for (int tm = 0; tm < 4; tm++)
#pragma unroll
            for (int tn = 0; tn < 4; tn++)
#pragma unroll
                for (int r = 0; r < 4; r++) {
                    const int ml = wm + tm * 16 + quad * 4 + r;
                    const int nl = wn + tn * 16 + l16;
                    CT[nl][ml] = (bf16)acc[tm][tn][r];
                }
        __syncthreads();
        const int nl = tid >> 1, part = tid & 1;
        const int n = bn + nl, h = n >> 6, d = n & 63;
        const int bbv = bm >> 11, s0v = bm & 2047;
        bf16* o = VT + (((size_t)(bbv * Hh + h)) * HDim + d) * Sq + s0v + part * 64;
#pragma unroll
        for (int i = 0; i < 8; i++)
            *(bf16x8*)(o + i * 8) = *(const bf16x8*)&CT[nl][part * 64 + i * 8];
    }
}

// ---------------------------------------------------------------------------
// Kernel 2: flash-style causal attention, S-transposed, fixed-reference
// softmax.  v6 = round-2 structure (q-sliced, best measured 60us) +
// round-4's layout-verified in-register P->PV:
//   - 4 waves x 16 qrows; QK^T gives sT[mt] = S^T[key=mt*16+quad*4+r][q=l16]
//     which IS the K=16 MFMA B-fragment per key-slice mt ->
//     PV = 16x mfma_f32_16x16x16bf16_1k, P never touches LDS.
//   - PlT deleted: LDS 40960 -> 32768 B -> 4 blocks/CU (was 3, quantized),
//     and the ds_write-P + ds_read-P (~250 cyc) leaves the critical path.
//   - acc is only 16 AGPR in q-sliced form -> no spill risk at (256,4)
//     (round-4's spill came from 64-AGPR acc + 128-reg cap; round 2 ran
//     (256,4) at VGPR 52).
// q-tiles paired {y, 31-y} (uniform 33 k-iters; 1024 blocks = 4/CU exact).
// Hot loop mask-free (diagonal peeled).  Double-buffered K/V DMA, counted
// s_waitcnt vmcnt(4) + raw s_barrier, setprio around MFMA clusters.
// ---------------------------------------------------------------------------
__global__ __launch_bounds__(256, 4)
void attn(const bf16* __restrict__ Qb, const bf16* __restrict__ Kb,
          const bf16* __restrict__ VTg, bf16* __restrict__ Cx)
{
    const int bh = blockIdx.x;                 // XCD = bh % 8
    const int bl = bh >> 4, h = bh & 15;

    __shared__ __align__(16) bf16 Kl[2][64][64];   // [buf][key][d], 16B-swizzled
    __shared__ __align__(16) bf16 Vt[2][64][64];   // [buf][d][key], 16B-swizzled

    const int tid  = threadIdx.x;
    const int wave = tid >> 6, lane = tid & 63, quad = lane >> 4, l16 = lane & 15;

    // staging geometry: wave stages rows wave*16 + {0,8} + (lane>>3)
    const int srow = wave * 16 + (lane >> 3);
    const int lb   = (lane & 7) ^ (lane >> 3);     // 16B-slot source swizzle

    for (int pass = 0; pass < 2; pass++) {
        const int qt = (pass == 0) ? (int)blockIdx.y : 31 - (int)blockIdx.y;
        const int q0 = qt * 64;
        const int nk = qt + 1;

        // Q^T B-fragment: col = qrow = q0 + wave*16 + l16
        bf16x8 bq[2];
        {
            const bf16* Qrow = Qb + ((size_t)bh * Sq + q0 + wave * 16 + l16) * HDim;
            bq[0] = *(const bf16x8*)(Qrow + quad * 8);
            bq[1] = *(const bf16x8*)(Qrow + 32 + quad * 8);
        }

        floatx4 acc[4];   // acc[db] = O^T[d = db*16 + quad*4 + r][q = wave*16 + l16]
#pragma unroll
        for (int i = 0; i < 4; i++) acc[i] = (floatx4){0.f, 0.f, 0.f, 0.f};
        float l_part = 0.f;

        const bf16* kp = Kb  + ((size_t)bh * Sq + srow) * HDim + lb * 8;
        const bf16* vp = VTg + ((size_t)bh * HDim + srow) * Sq + lb * 8;

        // issue the 4 DMA ops for one k-tile into buffer nb, advance pointers
        auto stage = [&](int nb) {
#pragma unroll
            for (int i = 0; i < 2; i++) {
                dma16((const void*)(kp + (size_t)(i * 8) * HDim), (void*)&Kl[nb][wave * 16 + i * 8][0]);
                dma16((const void*)(vp + (size_t)(i * 8) * Sq),  (void*)&Vt[nb][wave * 16 + i * 8][0]);
            }
            kp += 64 * HDim;
            vp += 64;
        };

        // compute one k-tile from buffer nb; MASKED known at compile time
        auto tile = [&](int nb, bool masked) {
            const bf16 (*Ksm)[64] = Kl[nb];
            const bf16 (*Vsm)[64] = Vt[nb];

            // S^T[key][qrow] = K · Q^T   (K pre-scaled to log2 domain)
            floatx4 sT[4];
            __builtin_amdgcn_s_setprio(1);
#pragma unroll
            for (int mt = 0; mt < 4; mt++) {
                const int kr = mt * 16 + l16;
                bf16x8 ak0 = *(const bf16x8*)&Ksm[kr][(quad ^ (kr & 7)) * 8];
                bf16x8 ak1 = *(const bf16x8*)&Ksm[kr][((4 + quad) ^ (kr & 7)) * 8];
                floatx4 z = (floatx4){0.f, 0.f, 0.f, 0.f};
                z = __builtin_amdgcn_mfma_f32_16x16x32_bf16(ak0, bq[0], z, 0, 0, 0);
                z = __builtin_amdgcn_mfma_f32_16x16x32_bf16(ak1, bq[1], z, 0, 0, 0);
                sT[mt] = z;
            }
            __builtin_amdgcn_s_setprio(0);

            if (masked) {   // diagonal tile: key(local) vs qrow(local)
#pragma unroll
                for (int mt = 0; mt < 4; mt++)
#pragma unroll
                    for (int r = 0; r < 4; r++) {
                        const int keyl  = mt * 16 + quad * 4 + r;
                        const int qrowl = wave * 16 + l16;
                        if (keyl > qrowl) sT[mt][r] = -1e30f;
                    }
            }

            // fixed-reference softmax: P = exp2(s) (bounded); per-lane sum;
            // pack P straight into K=16 PV B-fragments (keys quad*4+0..3, col l16)
            s16x4 pb[4];
            {
                float rs = 0.f;
#pragma unroll
                for (int mt = 0; mt < 4; mt++) {
#pragma unroll
                    for (int r = 0; r < 4; r++) {
                        const float e = __builtin_amdgcn_exp2f(sT[mt][r]);
                        sT[mt][r] = e;
                        rs += e;
                    }
                    const uint2 pk = make_uint2(pk_bf16(sT[mt][0], sT[mt][1]),
                                                pk_bf16(sT[mt][2], sT[mt][3]));
                    pb[mt] = __builtin_bit_cast(s16x4, pk);
                }
                l_part += rs;
            }

            // O^T += V^T · P^T via K=16 MFMA: A-frag = 4 bf16 of
            // V^T[d = db*16 + l16][key = mt*16 + quad*4 + 0..3]
            __builtin_amdgcn_s_setprio(1);
#pragma unroll
            for (int mt = 0; mt < 4; mt++) {
#pragma unroll
                for (int db = 0; db < 4; db++) {
                    const int row = db * 16 + l16;
                    const int sl  = ((mt * 2 + (quad >> 1)) ^ (row & 7)) * 16 + (quad & 1) * 8;
                    const uint2 v = *(const uint2*)((const char*)&Vsm[row][0] + sl);
                    const s16x4 av = __builtin_bit_cast(s16x4, v);
                    acc[db] = __builtin_amdgcn_mfma_f32_16x16x16bf16_1k(av, pb[mt], acc[db], 0, 0, 0);
                }
            }
            __builtin_amdgcn_s_setprio(0);
        };

        // pipelined loop: stage(t+1) in flight while computing tile t.
        // vmcnt(4): newest 4 vmem ops are tile t+1's DMAs.  RAW barrier:
        // each wave waited for its own loads pre-barrier -> all waves'
        // LDS writes visible.  End-of-iter barrier protects the buffer
        // about to be overwritten.
        stage(0);
        for (int kt = 0; kt < nk - 1; kt++) {
            const int cur = kt & 1;
            stage(cur ^ 1);
            asm volatile("s_waitcnt vmcnt(4)" ::: "memory");
            __builtin_amdgcn_s_barrier();
            tile(cur, false);
            __builtin_amdgcn_s_barrier();
        }
        asm volatile("s_waitcnt vmcnt(0)" ::: "memory");
        __builtin_amdgcn_s_barrier();
        tile((nk - 1) & 1, true);               // peeled diagonal tile
        __builtin_amdgcn_s_barrier();           // protect buffers for next pass

        // epilogue: one cross-quad reduce of l_sum, then O = acc / l_sum
        {
            float rs = l_part;
            rs += __shfl_xor(rs, 16, 64);
            rs += __shfl_xor(rs, 32, 64);
            const float inv = __builtin_amdgcn_rcpf(rs);
            const int qrow = q0 + wave * 16 + l16;
#pragma unroll
            for (int db = 0; db < 4; db++) {
                uint2 pk;
                pk.x = pk_bf16(acc[db][0] * inv, acc[db][1] * inv);
                pk.y = pk_bf16(acc[db][2] * inv, acc[db][3] * inv);
                *(uint2*)(Cx + ((size_t)(bl * Sq + qrow)) * Dm + h * HDim + db * 16 + quad * 4) = pk;
            }
        }
    }
}

// ---------------------------------------------------------------------------
// Kernel 3: output projection.  Cx bf16 @ WoT + bo -> fp32 out.
// grid (Mtiles, 8): XCD = Mtile%8 for A-tile L2 reuse.
// ---------------------------------------------------------------------------
__global__ __launch_bounds__(256, 2)
void out_gemm(const bf16* __restrict__ Cx, const bf16* __restrict__ WtO,
              const float* __restrict__ bo, float* __restrict__ out, int mbase)
{
    __shared__ __align__(16) bf16 As2[128][64];
    __shared__ __align__(16) bf16 Bs2[128][64];

    const int tid  = threadIdx.x;
    const int wave = tid >> 6, lane = tid & 63, quad = lane >> 4, l16 = lane & 15;
    const int bm = blockIdx.x * 128, bn = blockIdx.y * 128;
    const int wm = (wave >> 1) * 64, wn = (wave & 1) * 64;

    floatx4 acc[4][4];
#pragma unroll
    for (int i = 0; i < 4; i++)
#pragma unroll
        for (int j = 0; j < 4; j++) acc[i][j] = (floatx4){0.f, 0.f, 0.f, 0.f};

    for (int k0 = 0; k0 < 1024; k0 += 64) {
        __syncthreads();
#pragma unroll
        for (int i = 0; i < 4; i++) {
            const int row = wave * 32 + i * 8 + (lane >> 3);
            const int lb  = (lane & 7) ^ (row & 7);
            const bf16* ga = Cx  + (size_t)(bm + row) * 1024 + k0 + lb * 8;
            const bf16* gb = WtO + (size_t)(bn + row) * 1024 + k0 + lb * 8;
            dma16((const void*)ga, (void*)&As2[wave * 32 + i * 8][0]);
            dma16((const void*)gb, (void*)&Bs2[wave * 32 + i * 8][0]);
        }
        __syncthreads();

#pragma unroll
        for (int kk = 0; kk < 2; kk++) {
            bf16x8 a[4], b[4];
#pragma unroll
            for (int tm = 0; tm < 4; tm++) {
                const int m = wm + tm * 16 + l16;
                const int phys = (kk * 4 + quad) ^ (m & 7);
                a[tm] = *(const bf16x8*)&As2[m][phys * 8];
            }
#pragma unroll
            for (int tn = 0; tn < 4; tn++) {
                const int n = wn + tn * 16 + l16;
                const int phys = (kk * 4 + quad) ^ (n & 7);
                b[tn] = *(const bf16x8*)&Bs2[n][phys * 8];
            }
#pragma unroll
            for (int tm = 0; tm < 4; tm++)
#pragma unroll
                for (int tn = 0; tn < 4; tn++)
                    acc[tm][tn] = __builtin_amdgcn_mfma_f32_16x16x32_bf16(a[tm], b[tn], acc[tm][tn], 0, 0, 0);
        }
    }

#pragma unroll
    for (int tm = 0; tm < 4; tm++)
#pragma unroll
        for (int tn = 0; tn < 4; tn++)
#pragma unroll
            for (int r = 0; r < 4; r++) {
                const int m = bm + wm + tm * 16 + quad * 4 + r;
                const int n = bn + wn + tn * 16 + l16;
                out[(size_t)(mbase + m) * 1024 + n] = acc[tm][tn][r] + bo[n];
            }
}

// ---------------------------------------------------------------------------
extern "C" void kernel_launch(void* const* d_in, const int* in_sizes, int n_in,
                              void* d_out, int out_size, void* d_ws, size_t ws_size,
                              hipStream_t stream)
{
    const float* x  = (const float*)d_in[0];
    const float* Wq = (const float*)d_in[1];
    const float* Wk = (const float*)d_in[2];
    const float* Wv = (const float*)d_in[3];
    const float* Wo = (const float*)d_in[4];
    const float* bo = (const float*)d_in[5];
    float* out = (float*)d_out;

    const size_t M1 = 1024 * 1024;
    const size_t XE = (size_t)8192 * 1024;

    if (ws_size >= (size_t)72 * 1024 * 1024) {
        // primary: Wt 8MB | xb 16 (aliased by Cx) | Qb 16 | Kb 16 | VT 16
        bf16* Wt = (bf16*)d_ws;
        bf16* xb = Wt + 4 * M1;
        bf16* Qb = xb + XE;
        bf16* Kb = Qb + XE;
        bf16* VT = Kb + XE;
        bf16* Cx = xb;  // alias: xb dead after qkv_gemm

        prep_all<<<dim3(16, 16, 5), 256, 0, stream>>>(Wq, Wk, Wv, Wo, Wt, x, xb);
        qkv_gemm<1><<<dim3(64, 8, 3), 256, 0, stream>>>(x, xb, Wt, Qb, Kb, VT);
        attn<<<dim3(64, 16), 256, 0, stream>>>(Qb, Kb, VT, Cx);
        out_gemm<<<dim3(64, 8), 256, 0, stream>>>(Cx, Wt + 3 * M1, bo, out, 0);
    } else {
        // fallback (64 MB): Wt 8 | Qb 16 | Kb 16 | VT 16 | Cx 8
        bf16* Wt = (bf16*)d_ws;
        bf16* Qb = Wt + 4 * M1;
        bf16* Kb = Qb + XE;
        bf16* VT = Kb + XE;
        bf16* Cx = VT + XE;

        prep_all<<<dim3(16, 16, 4), 256, 0, stream>>>(Wq, Wk, Wv, Wo, Wt, nullptr, nullptr);
        qkv_gemm<0><<<dim3(64, 8, 3), 256, 0, stream>>>(x, nullptr, Wt, Qb, Kb, VT);
        const size_t chunk = (size_t)2 * Hh * Sq * HDim;
        for (int c = 0; c < 2; c++) {
            attn<<<dim3(32, 16), 256, 0, stream>>>(Qb + c * chunk, Kb + c * chunk,
                                                   VT + c * chunk, Cx);
            out_gemm<<<dim3(32, 8), 256, 0, stream>>>(Cx, Wt + 3 * M1, bo, out, c * 4096);
        }
    }
}

// Round 8
// 227.974 us; speedup vs baseline: 1.1976x; 1.0422x over previous
//
#include <hip/hip_runtime.h>
#include <math.h>
#include <stdint.h>

typedef __bf16 bf16;
typedef bf16 bf16x2 __attribute__((ext_vector_type(2)));
typedef bf16 bf16x8 __attribute__((ext_vector_type(8)));
typedef short s16x4 __attribute__((ext_vector_type(4)));
typedef float floatx4 __attribute__((ext_vector_type(4)));

static constexpr int Sq = 2048, Dm = 1024, Hh = 16, HDim = 64;

#define GAS __attribute__((address_space(1)))
#define LAS __attribute__((address_space(3)))

// async global->LDS DMA, 16 B per lane; lds base wave-uniform, lane i -> base + i*16
__device__ __forceinline__ void dma16(const void* g, void* l) {
    __builtin_amdgcn_global_load_lds((const GAS void*)g, (LAS void*)l, 16, 0, 0);
}

__device__ __forceinline__ uint32_t pk_bf16(float a, float b) {
    bf16x2 t;
    t[0] = (bf16)a;
    t[1] = (bf16)b;
    return __builtin_bit_cast(uint32_t, t);   // v_cvt_pk_bf16_f32 on gfx950
}

// ---------------------------------------------------------------------------
// Kernel 0: merged prep.  z<4: W fp32 [k][n] -> Wt bf16 [n][k] (w = z).
// z==4: x fp32 -> bf16 (256 blocks sweep 16x).
// ---------------------------------------------------------------------------
__global__ __launch_bounds__(256)
void prep_all(const float* __restrict__ Wq, const float* __restrict__ Wk,
              const float* __restrict__ Wv, const float* __restrict__ Wo,
              bf16* __restrict__ Wt,
              const float* __restrict__ x, bf16* __restrict__ xb)
{
    const int t = threadIdx.x;
    if (blockIdx.z == 4) {
        const int b = blockIdx.y * 16 + blockIdx.x;     // 0..255
        const size_t base = ((size_t)b * 256 + t) * 8;
#pragma unroll
        for (int it = 0; it < 16; it++) {
            const size_t i = base + (size_t)it * 524288;   // 256*256*8
            float4 f0 = *(const float4*)(x + i);
            float4 f1 = *(const float4*)(x + i + 4);
            bf16x8 v;
            v[0]=(bf16)f0.x; v[1]=(bf16)f0.y; v[2]=(bf16)f0.z; v[3]=(bf16)f0.w;
            v[4]=(bf16)f1.x; v[5]=(bf16)f1.y; v[6]=(bf16)f1.z; v[7]=(bf16)f1.w;
            *(bf16x8*)(xb + i) = v;
        }
        return;
    }
    const int w = blockIdx.z;
    const float* W = (w == 0) ? Wq : (w == 1) ? Wk : (w == 2) ? Wv : Wo;
    bf16* dst = Wt + (size_t)w * 1024 * 1024;
    const int k0 = blockIdx.x * 64, n0 = blockIdx.y * 64;
    __shared__ uint32_t Tl[64][33];
    {
        const int c8 = (t & 7) * 8;
        const int kp = t >> 3;
        const float* r0 = W + (size_t)(k0 + 2 * kp) * 1024 + n0 + c8;
        const float* r1 = r0 + 1024;
        float4 a0 = *(const float4*)r0, a1 = *(const float4*)(r0 + 4);
        float4 b0 = *(const float4*)r1, b1 = *(const float4*)(r1 + 4);
        float ra[8] = {a0.x, a0.y, a0.z, a0.w, a1.x, a1.y, a1.z, a1.w};
        float rb[8] = {b0.x, b0.y, b0.z, b0.w, b1.x, b1.y, b1.z, b1.w};
#pragma unroll
        for (int j = 0; j < 8; j++)
            Tl[c8 + j][kp] = pk_bf16(ra[j], rb[j]);
    }
    __syncthreads();
    {
        const int c = t >> 2, dq = (t & 3) * 8;
        uint32_t d[8];
#pragma unroll
        for (int i = 0; i < 8; i++) d[i] = Tl[c][dq + i];
        uint32_t* o = (uint32_t*)(dst + (size_t)(n0 + c) * 1024 + k0 + dq * 2);
        *(uint4*)o       = make_uint4(d[0], d[1], d[2], d[3]);
        *(uint4*)(o + 4) = make_uint4(d[4], d[5], d[6], d[7]);
    }
}

// ---------------------------------------------------------------------------
// Kernel 1: QKV projection.  AMODE=1: bf16 xb via DMA (primary);
// AMODE=0: fp32 x (fallback).  128x128 tile, BK=64.
// grid (64 Mtiles, 8 Ntiles, 3): XCD = Mtile%8 -> A-tile reuse in XCD L2.
// K output pre-scaled by 0.125*log2(e) (softmax runs in exp2 domain).
// VT is written KEY-PERMUTED within each 64-key tile (bits [5:4]<->[3:2]
// of the key index swapped, an involution) so attn's PV A-fragment read
// becomes two contiguous b128 per d-row (conflict-free with row-XOR).
// ---------------------------------------------------------------------------
template <int AMODE>
__global__ __launch_bounds__(256, 2)
void qkv_gemm(const float* __restrict__ x, const bf16* __restrict__ xb,
              const bf16* __restrict__ Wt,
              bf16* __restrict__ Qb, bf16* __restrict__ Kb, bf16* __restrict__ VT)
{
    const int zz = blockIdx.z;
    const bf16* Wsel = Wt + (size_t)zz * 1024 * 1024;

    __shared__ __align__(16) unsigned char smem[34816];
    bf16 (*As1)[64] = (bf16(*)[64])smem;
    bf16 (*As0)[72] = (bf16(*)[72])smem;
    bf16 (*Bs)[64]  = (bf16(*)[64])(smem + (AMODE ? 16384 : 18432));

    const int tid  = threadIdx.x;
    const int wave = tid >> 6, lane = tid & 63, quad = lane >> 4, l16 = lane & 15;
    const int bm = blockIdx.x * 128, bn = blockIdx.y * 128;   // XCD = blockIdx.x % 8
    const int wm = (wave >> 1) * 64, wn = (wave & 1) * 64;

    floatx4 acc[4][4];
#pragma unroll
    for (int i = 0; i < 4; i++)
#pragma unroll
        for (int j = 0; j < 4; j++) acc[i][j] = (floatx4){0.f, 0.f, 0.f, 0.f};

    for (int k0 = 0; k0 < 1024; k0 += 64) {
        __syncthreads();
#pragma unroll
        for (int i = 0; i < 4; i++) {
            const int row = wave * 32 + i * 8 + (lane >> 3);
            const int lb  = (lane & 7) ^ (row & 7);
            const bf16* g = Wsel + (size_t)(bn + row) * 1024 + k0 + lb * 8;
            dma16((const void*)g, (void*)&Bs[wave * 32 + i * 8][0]);
        }
        if (AMODE) {
#pragma unroll
            for (int i = 0; i < 4; i++) {
                const int row = wave * 32 + i * 8 + (lane >> 3);
                const int lb  = (lane & 7) ^ (row & 7);
                const bf16* g = xb + (size_t)(bm + row) * 1024 + k0 + lb * 8;
                dma16((const void*)g, (void*)&As1[wave * 32 + i * 8][0]);
            }
        } else {
#pragma unroll
            for (int it = 0; it < 2; it++) {
                const int r  = (tid >> 2) + it * 64;
                const int cq = (tid & 3) * 16;
                const float* src = x + (size_t)(bm + r) * 1024 + k0 + cq;
                float4 f0 = *(const float4*)src,       f1 = *(const float4*)(src + 4);
                float4 f2 = *(const float4*)(src + 8), f3 = *(const float4*)(src + 12);
                bf16x8 v0, v1;
                v0[0]=(bf16)f0.x; v0[1]=(bf16)f0.y; v0[2]=(bf16)f0.z; v0[3]=(bf16)f0.w;
                v0[4]=(bf16)f1.x; v0[5]=(bf16)f1.y; v0[6]=(bf16)f1.z; v0[7]=(bf16)f1.w;
                v1[0]=(bf16)f2.x; v1[1]=(bf16)f2.y; v1[2]=(bf16)f2.z; v1[3]=(bf16)f2.w;
                v1[4]=(bf16)f3.x; v1[5]=(bf16)f3.y; v1[6]=(bf16)f3.z; v1[7]=(bf16)f3.w;
                *(bf16x8*)&As0[r][cq]     = v0;
                *(bf16x8*)&As0[r][cq + 8] = v1;
            }
        }
        __syncthreads();

#pragma unroll
        for (int kk = 0; kk < 2; kk++) {
            bf16x8 a[4], b[4];
#pragma unroll
            for (int tm = 0; tm < 4; tm++) {
                const int m = wm + tm * 16 + l16;
                if (AMODE) {
                    const int phys = (kk * 4 + quad) ^ (m & 7);
                    a[tm] = *(const bf16x8*)&As1[m][phys * 8];
                } else {
                    a[tm] = *(const bf16x8*)&As0[m][kk * 32 + quad * 8];
                }
            }
#pragma unroll
            for (int tn = 0; tn < 4; tn++) {
                const int n = wn + tn * 16 + l16;
                const int phys = (kk * 4 + quad) ^ (n & 7);
                b[tn] = *(const bf16x8*)&Bs[n][phys * 8];
            }
#pragma unroll
            for (int tm = 0; tm < 4; tm++)
#pragma unroll
                for (int tn = 0; tn < 4; tn++)
                    acc[tm][tn] = __builtin_amdgcn_mfma_f32_16x16x32_bf16(a[tm], b[tn], acc[tm][tn], 0, 0, 0);
        }
    }

    if (zz < 2) {
        bf16* dst = (zz == 0) ? Qb : Kb;
        // K pre-scaled by 1/sqrt(64) * log2(e): softmax in exp2 domain
        const float sc = (zz == 1) ? 0.18033688f : 1.0f;
#pragma unroll
        for (int tm = 0; tm < 4; tm++)
#pragma unroll
            for (int tn = 0; tn < 4; tn++)
#pragma unroll
                for (int r = 0; r < 4; r++) {
                    const int m = bm + wm + tm * 16 + quad * 4 + r;
                    const int n = bn + wn + tn * 16 + l16;
                    const int bb = m >> 11, s = m & 2047;
                    const int h = n >> 6, d = n & 63;
                    dst[(((size_t)(bb * Hh + h)) * Sq + s) * HDim + d] = (bf16)(acc[tm][tn][r] * sc);
                }
    } else {
        __syncthreads();
        bf16 (*CT)[136] = (bf16(*)[136])smem;
#pragma unroll
        for (int tm = 0; tm < 4; tm++)
#pragma unroll
            for (int tn = 0; tn < 4; tn++)
#pragma unroll
                for (int r = 0; r < 4; r++) {
                    const int ml = wm + tm * 16 + quad * 4 + r;
                    const int nl = wn + tn * 16 + l16;
                    // key-permute within 64-key tile: swap bits [5:4]<->[3:2]
                    const int pml = (ml & 0x43) | ((ml & 0x30) >> 2) | ((ml & 0x0C) << 2);
                    CT[nl][pml] = (bf16)acc[tm][tn][r];
                }
        __syncthreads();
        const int nl = tid >> 1, part = tid & 1;
        const int n = bn + nl, h = n >> 6, d = n & 63;
        const int bbv = bm >> 11, s0v = bm & 2047;
        bf16* o = VT + (((size_t)(bbv * Hh + h)) * HDim + d) * Sq + s0v + part * 64;
#pragma unroll
        for (int i = 0; i < 8; i++)
            *(bf16x8*)(o + i * 8) = *(const bf16x8*)&CT[nl][part * 64 + i * 8];
    }
}

// ---------------------------------------------------------------------------
// Kernel 2: flash-style causal attention, S-transposed, fixed-reference
// softmax.  v7 = v6 (q-sliced, in-register P->PV via K=16 MFMA) with the
// PV V-read converted from 16x ds_read_b64 (4-way bank conflict, even
// banks only -> 8.65M conflicts, ~14us) to 8x ds_read_b128 using the same
// row-XOR pattern as the proven-free K-read.  Enabled by VT's key
// permutation (bits [5:4]<->[3:2]): lane(quad)'s four PV A-frags (keys
// mt*16+quad*4+r, all mt) are 32 CONTIGUOUS bytes = chunks 2q,2q+1.
// LDS 32768 B, VGPR ~44 -> 4 blocks/CU.  q-tiles paired {y,31-y}, hot
// loop mask-free, double-buffered DMA + vmcnt(4), raw barriers, setprio.
// ---------------------------------------------------------------------------
__global__ __launch_bounds__(256, 4)
void attn(const bf16* __restrict__ Qb, const bf16* __restrict__ Kb,
          const bf16* __restrict__ VTg, bf16* __restrict__ Cx)
{
    const int bh = blockIdx.x;                 // XCD = bh % 8
    const int bl = bh >> 4, h = bh & 15;

    __shared__ __align__(16) bf16 Kl[2][64][64];   // [buf][key][d], 16B-swizzled
    __shared__ __align__(16) bf16 Vt[2][64][64];   // [buf][d][key-permuted], 16B-swizzled

    const int tid  = threadIdx.x;
    const int wave = tid >> 6, lane = tid & 63, quad = lane >> 4, l16 = lane & 15;

    // staging geometry: wave stages rows wave*16 + {0,8} + (lane>>3)
    const int srow = wave * 16 + (lane >> 3);
    const int lb   = (lane & 7) ^ (lane >> 3);     // 16B-slot source swizzle

    for (int pass = 0; pass < 2; pass++) {
        const int qt = (pass == 0) ? (int)blockIdx.y : 31 - (int)blockIdx.y;
        const int q0 = qt * 64;
        const int nk = qt + 1;

        // Q^T B-fragment: col = qrow = q0 + wave*16 + l16
        bf16x8 bq[2];
        {
            const bf16* Qrow = Qb + ((size_t)bh * Sq + q0 + wave * 16 + l16) * HDim;
            bq[0] = *(const bf16x8*)(Qrow + quad * 8);
            bq[1] = *(const bf16x8*)(Qrow + 32 + quad * 8);
        }

        floatx4 acc[4];   // acc[db] = O^T[d = db*16 + quad*4 + r][q = wave*16 + l16]
#pragma unroll
        for (int i = 0; i < 4; i++) acc[i] = (floatx4){0.f, 0.f, 0.f, 0.f};
        float l_part = 0.f;

        const bf16* kp = Kb  + ((size_t)bh * Sq + srow) * HDim + lb * 8;
        const bf16* vp = VTg + ((size_t)bh * HDim + srow) * Sq + lb * 8;

        // issue the 4 DMA ops for one k-tile into buffer nb, advance pointers
        auto stage = [&](int nb) {
#pragma unroll
            for (int i = 0; i < 2; i++) {
                dma16((const void*)(kp + (size_t)(i * 8) * HDim), (void*)&Kl[nb][wave * 16 + i * 8][0]);
                dma16((const void*)(vp + (size_t)(i * 8) * Sq),  (void*)&Vt[nb][wave * 16 + i * 8][0]);
            }
            kp += 64 * HDim;
            vp += 64;
        };

        // compute one k-tile from buffer nb; MASKED known at compile time
        auto tile = [&](int nb, bool masked) {
            const bf16 (*Ksm)[64] = Kl[nb];
            const bf16 (*Vsm)[64] = Vt[nb];

            // S^T[key][qrow] = K · Q^T   (K pre-scaled to log2 domain)
            floatx4 sT[4];
            __builtin_amdgcn_s_setprio(1);
#pragma unroll
            for (int mt = 0; mt < 4; mt++) {
                const int kr = mt * 16 + l16;
                bf16x8 ak0 = *(const bf16x8*)&Ksm[kr][(quad ^ (kr & 7)) * 8];
                bf16x8 ak1 = *(const bf16x8*)&Ksm[kr][((4 + quad) ^ (kr & 7)) * 8];
                floatx4 z = (floatx4){0.f, 0.f, 0.f, 0.f};
                z = __builtin_amdgcn_mfma_f32_16x16x32_bf16(ak0, bq[0], z, 0, 0, 0);
                z = __builtin_amdgcn_mfma_f32_16x16x32_bf16(ak1, bq[1], z, 0, 0, 0);
                sT[mt] = z;
            }
            __builtin_amdgcn_s_setprio(0);

            if (masked) {   // diagonal tile: key(local) vs qrow(local)
#pragma unroll
                for (int mt = 0; mt < 4; mt++)
#pragma unroll
                    for (int r = 0; r < 4; r++) {
                        const int keyl  = mt * 16 + quad * 4 + r;
                        const int qrowl = wave * 16 + l16;
                        if (keyl > qrowl) sT[mt][r] = -1e30f;
                    }
            }

            // fixed-reference softmax: P = exp2(s) (bounded); per-lane sum;
            // pack P straight into K=16 PV B-fragments (keys quad*4+0..3, col l16)
            s16x4 pb[4];
            {
                float rs = 0.f;
#pragma unroll
                for (int mt = 0; mt < 4; mt++) {
#pragma unroll
                    for (int r = 0; r < 4; r++) {
                        const float e = __builtin_amdgcn_exp2f(sT[mt][r]);
                        sT[mt][r] = e;
                        rs += e;
                    }
                    const uint2 pk = make_uint2(pk_bf16(sT[mt][0], sT[mt][1]),
                                                pk_bf16(sT[mt][2], sT[mt][3]));
                    pb[mt] = __builtin_bit_cast(s16x4, pk);
                }
                l_part += rs;
            }

            // O^T += V^T · P^T via K=16 MFMA.  Permuted Vt: lane(quad)'s
            // A-frags for all 4 mt live at chunks 2q,2q+1 (^ row-XOR) ->
            // two b128 per d-block, same conflict-free pattern as K-read.
            __builtin_amdgcn_s_setprio(1);
#pragma unroll
            for (int db = 0; db < 4; db++) {
                const int row = db * 16 + l16;
#pragma unroll
                for (int p = 0; p < 2; p++) {
                    const int phys = ((quad * 2 + p) ^ (row & 7)) * 16;
                    const uint4 v = *(const uint4*)((const char*)&Vsm[row][0] + phys);
                    const s16x4 av0 = __builtin_bit_cast(s16x4, make_uint2(v.x, v.y));
                    const s16x4 av1 = __builtin_bit_cast(s16x4, make_uint2(v.z, v.w));
                    acc[db] = __builtin_amdgcn_mfma_f32_16x16x16bf16_1k(av0, pb[2 * p],     acc[db], 0, 0, 0);
                    acc[db] = __builtin_amdgcn_mfma_f32_16x16x16bf16_1k(av1, pb[2 * p + 1], acc[db], 0, 0, 0);
                }
            }
            __builtin_amdgcn_s_setprio(0);
        };

        // pipelined loop: stage(t+1) in flight while computing tile t.
        // vmcnt(4): newest 4 vmem ops are tile t+1's DMAs.  RAW barrier:
        // each wave waited for its own loads pre-barrier -> all waves'
        // LDS writes visible.  End-of-iter barrier protects the buffer
        // about to be overwritten.
        stage(0);
        for (int kt = 0; kt < nk - 1; kt++) {
            const int cur = kt & 1;
            stage(cur ^ 1);
            asm volatile("s_waitcnt vmcnt(4)" ::: "memory");
            __builtin_amdgcn_s_barrier();
            tile(cur, false);
            __builtin_amdgcn_s_barrier();
        }
        asm volatile("s_waitcnt vmcnt(0)" ::: "memory");
        __builtin_amdgcn_s_barrier();
        tile((nk - 1) & 1, true);               // peeled diagonal tile
        __builtin_amdgcn_s_barrier();           // protect buffers for next pass

        // epilogue: one cross-quad reduce of l_sum, then O = acc / l_sum
        {
            float rs = l_part;
            rs += __shfl_xor(rs, 16, 64);
            rs += __shfl_xor(rs, 32, 64);
            const float inv = __builtin_amdgcn_rcpf(rs);
            const int qrow = q0 + wave * 16 + l16;
#pragma unroll
            for (int db = 0; db < 4; db++) {
                uint2 pk;
                pk.x = pk_bf16(acc[db][0] * inv, acc[db][1] * inv);
                pk.y = pk_bf16(acc[db][2] * inv, acc[db][3] * inv);
                *(uint2*)(Cx + ((size_t)(bl * Sq + qrow)) * Dm + h * HDim + db * 16 + quad * 4) = pk;
            }
        }
    }
}

// ---------------------------------------------------------------------------
// Kernel 3: output projection.  Cx bf16 @ WoT + bo -> fp32 out.
// grid (Mtiles, 8): XCD = Mtile%8 for A-tile L2 reuse.
// ---------------------------------------------------------------------------
__global__ __launch_bounds__(256, 2)
void out_gemm(const bf16* __restrict__ Cx, const bf16* __restrict__ WtO,
              const float* __restrict__ bo, float* __restrict__ out, int mbase)
{
    __shared__ __align__(16) bf16 As2[128][64];
    __shared__ __align__(16) bf16 Bs2[128][64];

    const int tid  = threadIdx.x;
    const int wave = tid >> 6, lane = tid & 63, quad = lane >> 4, l16 = lane & 15;
    const int bm = blockIdx.x * 128, bn = blockIdx.y * 128;
    const int wm = (wave >> 1) * 64, wn = (wave & 1) * 64;

    floatx4 acc[4][4];
#pragma unroll
    for (int i = 0; i < 4; i++)
#pragma unroll
        for (int j = 0; j < 4; j++) acc[i][j] = (floatx4){0.f, 0.f, 0.f, 0.f};

    for (int k0 = 0; k0 < 1024; k0 += 64) {
        __syncthreads();
#pragma unroll
        for (int i = 0; i < 4; i++) {
            const int row = wave * 32 + i * 8 + (lane >> 3);
            const int lb  = (lane & 7) ^ (row & 7);
            const bf16* ga = Cx  + (size_t)(bm + row) * 1024 + k0 + lb * 8;
            const bf16* gb = WtO + (size_t)(bn + row) * 1024 + k0 + lb * 8;
            dma16((const void*)ga, (void*)&As2[wave * 32 + i * 8][0]);
            dma16((const void*)gb, (void*)&Bs2[wave * 32 + i * 8][0]);
        }
        __syncthreads();

#pragma unroll
        for (int kk = 0; kk < 2; kk++) {
            bf16x8 a[4], b[4];
#pragma unroll
            for (int tm = 0; tm < 4; tm++) {
                const int m = wm + tm * 16 + l16;
                const int phys = (kk * 4 + quad) ^ (m & 7);
                a[tm] = *(const bf16x8*)&As2[m][phys * 8];
            }
#pragma unroll
            for (int tn = 0; tn < 4; tn++) {
                const int n = wn + tn * 16 + l16;
                const int phys = (kk * 4 + quad) ^ (n & 7);
                b[tn] = *(const bf16x8*)&Bs2[n][phys * 8];
            }
#pragma unroll
            for (int tm = 0; tm < 4; tm++)
#pragma unroll
                for (int tn = 0; tn < 4; tn++)
                    acc[tm][tn] = __builtin_amdgcn_mfma_f32_16x16x32_bf16(a[tm], b[tn], acc[tm][tn], 0, 0, 0);
        }
    }

#pragma unroll
    for (int tm = 0; tm < 4; tm++)
#pragma unroll
        for (int tn = 0; tn < 4; tn++)
#pragma unroll
            for (int r = 0; r < 4; r++) {
                const int m = bm + wm + tm * 16 + quad * 4 + r;
                const int n = bn + wn + tn * 16 + l16;
                out[(size_t)(mbase + m) * 1024 + n] = acc[tm][tn][r] + bo[n];
            }
}

// ---------------------------------------------------------------------------
extern "C" void kernel_launch(void* const* d_in, const int* in_sizes, int n_in,
                              void* d_out, int out_size, void* d_ws, size_t ws_size,
                              hipStream_t stream)
{
    const float* x  = (const float*)d_in[0];
    const float* Wq = (const float*)d_in[1];
    const float* Wk = (const float*)d_in[2];
    const float* Wv = (const float*)d_in[3];
    const float* Wo = (const float*)d_in[4];
    const float* bo = (const float*)d_in[5];
    float* out = (float*)d_out;

    const size_t M1 = 1024 * 1024;
    const size_t XE = (size_t)8192 * 1024;

    if (ws_size >= (size_t)72 * 1024 * 1024) {
        // primary: Wt 8MB | xb 16 (aliased by Cx) | Qb 16 | Kb 16 | VT 16
        bf16* Wt = (bf16*)d_ws;
        bf16* xb = Wt + 4 * M1;
        bf16* Qb = xb + XE;
        bf16* Kb = Qb + XE;
        bf16* VT = Kb + XE;
        bf16* Cx = xb;  // alias: xb dead after qkv_gemm

        prep_all<<<dim3(16, 16, 5), 256, 0, stream>>>(Wq, Wk, Wv, Wo, Wt, x, xb);
        qkv_gemm<1><<<dim3(64, 8, 3), 256, 0, stream>>>(x, xb, Wt, Qb, Kb, VT);
        attn<<<dim3(64, 16), 256, 0, stream>>>(Qb, Kb, VT, Cx);
        out_gemm<<<dim3(64, 8), 256, 0, stream>>>(Cx, Wt + 3 * M1, bo, out, 0);
    } else {
        // fallback (64 MB): Wt 8 | Qb 16 | Kb 16 | VT 16 | Cx 8
        bf16* Wt = (bf16*)d_ws;
        bf16* Qb = Wt + 4 * M1;
        bf16* Kb = Qb + XE;
        bf16* VT = Kb + XE;
        bf16* Cx = VT + XE;

        prep_all<<<dim3(16, 16, 4), 256, 0, stream>>>(Wq, Wk, Wv, Wo, Wt, nullptr, nullptr);
        qkv_gemm<0><<<dim3(64, 8, 3), 256, 0, stream>>>(x, nullptr, Wt, Qb, Kb, VT);
        const size_t chunk = (size_t)2 * Hh * Sq * HDim;
        for (int c = 0; c < 2; c++) {
            attn<<<dim3(32, 16), 256, 0, stream>>>(Qb + c * chunk, Kb + c * chunk,
                                                   VT + c * chunk, Cx);
            out_gemm<<<dim3(32, 8), 256, 0, stream>>>(Cx, Wt + 3 * M1, bo, out, c * 4096);
        }
    }
}